// Round 13
// baseline (490.472 us; speedup 1.0000x reference)
//
#include <hip/hip_runtime.h>
#include <float.h>
#include <math.h>

constexpr int NN  = 30000;   // nodes
constexpr int EE  = 300000;  // edges before self-loops
constexpr int GG  = 1024;    // graphs
constexpr int HID = 256;
constexpr int NH  = 8;       // heads
constexpr int EP  = EE + NN; // edges incl self-loops
constexpr int NP  = 30080;   // padded rows: 235 * 128
constexpr int NB  = (NN + 255) / 256;  // 118 scan blocks

typedef short bf16x8 __attribute__((ext_vector_type(8)));
typedef float f32x4 __attribute__((ext_vector_type(4)));

__device__ __forceinline__ void gload_lds16(const void* g, void* l) {
    __builtin_amdgcn_global_load_lds(
        (const __attribute__((address_space(1))) unsigned int*)g,
        (__attribute__((address_space(3))) unsigned int*)l, 16, 0, 0);
}

__device__ __forceinline__ void f2hilo(float x, unsigned short& h, unsigned short& l) {
    unsigned u = __float_as_uint(x);
    h = (unsigned short)(u >> 16);                       // truncated hi
    float hv = __uint_as_float(u & 0xFFFF0000u);
    float r = x - hv;                                    // exact residual
    unsigned v = __float_as_uint(r);
    unsigned rnd = ((v >> 16) & 1u) + 0x7FFFu;           // RNE to bf16
    l = (unsigned short)((v + rnd) >> 16);
}

__device__ __forceinline__ float bf2f(unsigned short u) {
    return __uint_as_float(((unsigned)u) << 16);
}

// ---------------- CSR build ----------------
__global__ void k_hist(const int* __restrict__ edst, int* __restrict__ cnt) {
    int i = blockIdx.x * blockDim.x + threadIdx.x;
    if (i >= EP) return;
    int d = (i < EE) ? edst[i] : (i - EE);
    atomicAdd(&cnt[d], 1);
}

// parallel scan: per-block sums
__global__ void k_scan1(const int* __restrict__ cnt, int* __restrict__ bsum) {
    int tid = threadIdx.x, lane = tid & 63, wid = tid >> 6;
    int i = blockIdx.x * 256 + tid;
    int v = (i < NN) ? cnt[i] : 0;
    #pragma unroll
    for (int off = 32; off >= 1; off >>= 1) v += __shfl_xor(v, off, 64);
    __shared__ int ws[4];
    if (lane == 0) ws[wid] = v;
    __syncthreads();
    if (tid == 0) bsum[blockIdx.x] = ws[0] + ws[1] + ws[2] + ws[3];
}

// scan the 118 block sums (1 block, 128 threads)
__global__ void k_scan2(const int* __restrict__ bsum, int* __restrict__ boff,
                        int* __restrict__ indptr) {
    int tid = threadIdx.x, lane = tid & 63, wid = tid >> 6;
    int v = (tid < NB) ? bsum[tid] : 0;
    int incl = v;
    #pragma unroll
    for (int off = 1; off < 64; off <<= 1) {
        int t = __shfl_up(incl, off, 64);
        if (lane >= off) incl += t;
    }
    __shared__ int ws[2];
    if (lane == 63) ws[wid] = incl;
    __syncthreads();
    int pre = (wid == 1) ? ws[0] : 0;
    if (tid < NB) boff[tid] = pre + incl - v;  // exclusive
    if (tid == 0) indptr[NN] = ws[0] + ws[1];
}

// in-block exclusive scan + block offset
__global__ void k_scan3(const int* __restrict__ cnt, const int* __restrict__ boff,
                        int* __restrict__ indptr) {
    int tid = threadIdx.x, lane = tid & 63, wid = tid >> 6;
    int i = blockIdx.x * 256 + tid;
    int v = (i < NN) ? cnt[i] : 0;
    int incl = v;
    #pragma unroll
    for (int off = 1; off < 64; off <<= 1) {
        int t = __shfl_up(incl, off, 64);
        if (lane >= off) incl += t;
    }
    __shared__ int ws[4];
    if (lane == 63) ws[wid] = incl;
    __syncthreads();
    int pre = 0;
    for (int w = 0; w < wid; ++w) pre += ws[w];
    if (i < NN) indptr[i] = boff[blockIdx.x] + pre + incl - v;
}

__global__ void k_fill(const int* __restrict__ esrc, const int* __restrict__ edst,
                       const int* __restrict__ indptr, int* __restrict__ cursor,
                       int* __restrict__ srcs) {
    int i = blockIdx.x * blockDim.x + threadIdx.x;
    if (i >= EP) return;
    int d, s;
    if (i < EE) { d = edst[i]; s = esrc[i]; } else { d = i - EE; s = i - EE; }
    int pos = indptr[d] + atomicAdd(&cursor[d], 1);
    srcs[pos] = s;
}

// sort each segment -> deterministic slot order independent of atomic timing
__global__ void k_sortseg(int* __restrict__ srcs, const int* __restrict__ indptr) {
    int node = blockIdx.x * blockDim.x + threadIdx.x;
    if (node >= NN) return;
    int b = indptr[node], e = indptr[node + 1];
    for (int i = b + 1; i < e; ++i) {
        int v = srcs[i];
        int j = i - 1;
        while (j >= b && srcs[j] > v) { srcs[j + 1] = srcs[j]; --j; }
        srcs[j + 1] = v;
    }
}

__global__ void k_starts(const int* __restrict__ batch, int* __restrict__ starts) {
    int i = blockIdx.x * blockDim.x + threadIdx.x;
    if (i >= NN) return;
    int b = batch[i];
    if (i == 0 || batch[i - 1] != b) starts[b] = i;
    if (i == NN - 1) starts[GG] = NN;
}

// ---------------- weight split fp32 -> bf16 hi/lo ----------------
__global__ void k_wconv(const float* __restrict__ W1, const float* __restrict__ W2,
                        const float* __restrict__ W3, const float* __restrict__ W4,
                        const float* __restrict__ W5,
                        unsigned short* __restrict__ Whi, unsigned short* __restrict__ Wlo) {
    int i = blockIdx.x * blockDim.x + threadIdx.x;  // 0..65535
    int l = blockIdx.y;
    const float* W = (l == 0) ? W1 : (l == 1) ? W2 : (l == 2) ? W3 : (l == 3) ? W4 : W5;
    unsigned short h, lo;
    f2hilo(W[i], h, lo);
    Whi[(size_t)l * 65536 + i] = h;
    Wlo[(size_t)l * 65536 + i] = lo;
}

// folded score weights for all 5 layers in one launch:
// wt[l][t][k] = sum_c a[l][h,c]*W[l][h*32+c,k], t = h*2+type; bf16 hi/lo
__global__ void k_wtilde(const float* __restrict__ W1, const float* __restrict__ W2,
                         const float* __restrict__ W3, const float* __restrict__ W4,
                         const float* __restrict__ W5,
                         const float* __restrict__ as1, const float* __restrict__ as2,
                         const float* __restrict__ as3, const float* __restrict__ as4,
                         const float* __restrict__ as5,
                         const float* __restrict__ ad1, const float* __restrict__ ad2,
                         const float* __restrict__ ad3, const float* __restrict__ ad4,
                         const float* __restrict__ ad5,
                         unsigned short* __restrict__ Wthi, unsigned short* __restrict__ Wtlo) {
    int t = blockIdx.x;          // 0..15
    int l = blockIdx.y;          // 0..4
    int k = threadIdx.x;         // 0..255
    const float* W  = (l == 0) ? W1 : (l == 1) ? W2 : (l == 2) ? W3 : (l == 3) ? W4 : W5;
    const float* as = (l == 0) ? as1 : (l == 1) ? as2 : (l == 2) ? as3 : (l == 3) ? as4 : as5;
    const float* ad = (l == 0) ? ad1 : (l == 1) ? ad2 : (l == 2) ? ad3 : (l == 3) ? ad4 : ad5;
    int h = t >> 1, type = t & 1;
    const float* a = type ? ad : as;
    float v = 0.f;
    for (int c = 0; c < 32; ++c)
        v = fmaf(a[h * 32 + c], W[(size_t)(h * 32 + c) * HID + k], v);
    unsigned short hi, lo;
    f2hilo(v, hi, lo);
    Wthi[(size_t)l * 16 * HID + t * 256 + k] = hi;
    Wtlo[(size_t)l * 16 * HID + t * 256 + k] = lo;
}

// ---------------- embedding with max_norm=1 -> hi/lo ----------------
__global__ void k_embed(const int* __restrict__ ids, const float* __restrict__ emb,
                        unsigned short* __restrict__ Phi, unsigned short* __restrict__ Plo) {
    int w = (blockIdx.x * blockDim.x + threadIdx.x) >> 6;
    if (w >= NN) return;
    int lane = threadIdx.x & 63;
    const float4 v = *(const float4*)(emb + (size_t)ids[w] * HID + lane * 4);
    float ss = v.x * v.x + v.y * v.y + v.z * v.z + v.w * v.w;
    #pragma unroll
    for (int off = 32; off >= 1; off >>= 1) ss += __shfl_xor(ss, off, 64);
    float nrm = sqrtf(ss);
    float sc = fminf(1.0f, 1.0f / (nrm + 1e-12f));
    float o[4] = {v.x * sc, v.y * sc, v.z * sc, v.w * sc};
    ushort4 hv, lv;
    f2hilo(o[0], hv.x, lv.x); f2hilo(o[1], hv.y, lv.y);
    f2hilo(o[2], hv.z, lv.z); f2hilo(o[3], hv.w, lv.w);
    *(ushort4*)(Phi + (size_t)w * HID + lane * 4) = hv;
    *(ushort4*)(Plo + (size_t)w * HID + lane * 4) = lv;
}

// ---------------- split-bf16 MFMA GEMM + fused folded-score columns ----------------
// 512 threads / 8 waves; T3 2-phase: STAGE(kt+1) issued BEFORE compute(kt),
// double-buffered 128KB LDS, one barrier per kt (loads fly during MFMA).
__global__ __launch_bounds__(512) void k_gemm(const unsigned short* __restrict__ Ahi,
                                              const unsigned short* __restrict__ Alo,
                                              const unsigned short* __restrict__ Bhi,
                                              const unsigned short* __restrict__ Blo,
                                              const unsigned short* __restrict__ Wthi,
                                              const unsigned short* __restrict__ Wtlo,
                                              float* __restrict__ O,
                                              float* __restrict__ es,
                                              float* __restrict__ ed, int M) {
    __shared__ unsigned short lds[2][4][128 * 64];  // dbuf x {Ahi,Alo,Bhi,Blo}: 128KB
    const int tid = threadIdx.x;
    const int m0 = blockIdx.x * 128;
    const int n0 = blockIdx.y * 128;
    const int wid = tid >> 6, lane = tid & 63;
    const int wm = wid >> 1, wn = wid & 1;          // wm 0..3, wn 0..1
    const int r16 = lane & 15, kq = lane >> 4;
    const bool doScore = (blockIdx.y == 1);

    auto stage = [&](int buf, int kt) {
        const int kk = kt * 64;
        #pragma unroll
        for (int rnd = 0; rnd < 2; ++rnd) {
            int q = rnd * 512 + tid;                 // 0..1023
            int row = q >> 3, c = q & 7;
            int sc = c ^ (row & 7);
            size_t goffA = (size_t)(m0 + row) * HID + kk + sc * 8;
            size_t goffB = (size_t)(n0 + row) * HID + kk + sc * 8;
            gload_lds16(Ahi + goffA, &lds[buf][0][q * 8]);
            gload_lds16(Alo + goffA, &lds[buf][1][q * 8]);
            gload_lds16(Bhi + goffB, &lds[buf][2][q * 8]);
            gload_lds16(Blo + goffB, &lds[buf][3][q * 8]);
        }
    };

    f32x4 acc[2][4];
    f32x4 acc_s[2];   // score accumulators: this wave handles ks == wn half of rows (wm, f)
    acc_s[0] = (f32x4){0.f, 0.f, 0.f, 0.f};
    acc_s[1] = (f32x4){0.f, 0.f, 0.f, 0.f};
    #pragma unroll
    for (int i = 0; i < 2; ++i)
        #pragma unroll
        for (int j = 0; j < 4; ++j) acc[i][j] = (f32x4){0.f, 0.f, 0.f, 0.f};

    stage(0, 0);
    __syncthreads();
    int cur = 0;
    for (int kt = 0; kt < 4; ++kt) {
        const int kk = kt * 64;
        if (kt < 3) stage(cur ^ 1, kt + 1);   // issue next tile loads BEFORE compute
        #pragma unroll
        for (int ks = 0; ks < 2; ++ks) {
            bf16x8 ah[2], al[2], bh[4], bl[4];
            #pragma unroll
            for (int f = 0; f < 2; ++f) {
                int rowa = wm * 32 + f * 16 + r16;
                int ca = (ks * 4 + kq) ^ (rowa & 7);
                int offa = rowa * 64 + ca * 8;
                ah[f] = *(const bf16x8*)&lds[cur][0][offa];
                al[f] = *(const bf16x8*)&lds[cur][1][offa];
            }
            #pragma unroll
            for (int f = 0; f < 4; ++f) {
                int rowb = wn * 64 + f * 16 + r16;
                int cb = (ks * 4 + kq) ^ (rowb & 7);
                int offb = rowb * 64 + cb * 8;
                bh[f] = *(const bf16x8*)&lds[cur][2][offb];
                bl[f] = *(const bf16x8*)&lds[cur][3][offb];
            }
            #pragma unroll
            for (int mi = 0; mi < 2; ++mi)
                #pragma unroll
                for (int ni = 0; ni < 4; ++ni) {
                    acc[mi][ni] = __builtin_amdgcn_mfma_f32_16x16x32_bf16(ah[mi], bh[ni], acc[mi][ni], 0, 0, 0);
                    acc[mi][ni] = __builtin_amdgcn_mfma_f32_16x16x32_bf16(ah[mi], bl[ni], acc[mi][ni], 0, 0, 0);
                    acc[mi][ni] = __builtin_amdgcn_mfma_f32_16x16x32_bf16(al[mi], bh[ni], acc[mi][ni], 0, 0, 0);
                }
            if (doScore && wn == ks) {
                const size_t wtoff = (size_t)r16 * HID + kk + ks * 32 + kq * 8;
                bf16x8 wth = *(const bf16x8*)(Wthi + wtoff);
                bf16x8 wtl = *(const bf16x8*)(Wtlo + wtoff);
                #pragma unroll
                for (int ml = 0; ml < 2; ++ml) {
                    acc_s[ml] = __builtin_amdgcn_mfma_f32_16x16x32_bf16(ah[ml], wth, acc_s[ml], 0, 0, 0);
                    acc_s[ml] = __builtin_amdgcn_mfma_f32_16x16x32_bf16(ah[ml], wtl, acc_s[ml], 0, 0, 0);
                    acc_s[ml] = __builtin_amdgcn_mfma_f32_16x16x32_bf16(al[ml], wth, acc_s[ml], 0, 0, 0);
                }
            }
        }
        __syncthreads();   // drains next-tile loads (issued pre-compute) + guards buffer swap
        cur ^= 1;
    }
    // C/D layout: col = lane&15, row = (lane>>4)*4 + reg  [m89-verified]
    #pragma unroll
    for (int mi = 0; mi < 2; ++mi) {
        #pragma unroll
        for (int q = 0; q < 4; ++q) {
            int row = m0 + wm * 32 + mi * 16 + kq * 4 + q;
            if (row < M) {
                #pragma unroll
                for (int ni = 0; ni < 4; ++ni)
                    O[(size_t)row * HID + n0 + wn * 64 + ni * 16 + r16] = acc[mi][ni][q];
            }
        }
    }
    if (doScore) {
        // combine ks-halves per row-fragment (wm, ml): wn==1 writes partials, wn==0 adds + stores
        float* sl = (float*)&lds[0][0][0];  // scratch, main loop done
        if (wn == 1) {
            #pragma unroll
            for (int ml = 0; ml < 2; ++ml)
                *(f32x4*)&sl[((wm * 2 + ml) * 64 + lane) * 4] = acc_s[ml];
        }
        __syncthreads();
        if (wn == 0) {
            int h = r16 >> 1;
            #pragma unroll
            for (int ml = 0; ml < 2; ++ml) {
                f32x4 o = *(const f32x4*)&sl[((wm * 2 + ml) * 64 + lane) * 4];
                o += acc_s[ml];
                #pragma unroll
                for (int q = 0; q < 4; ++q) {
                    int row = m0 + wm * 32 + ml * 16 + kq * 4 + q;
                    if (row < M) {
                        if ((r16 & 1) == 0) es[row * NH + h] = o[q];
                        else               ed[row * NH + h] = o[q];
                    }
                }
            }
        }
    }
}

// ---------------- single-pass softmax-aggregate (R5 body; 2-wave blocks) ----------------
__global__ __launch_bounds__(128) void k_aggregate(const float* __restrict__ H,
                                                   const float* __restrict__ es,
                                                   const float* __restrict__ ed,
                                                   const int* __restrict__ indptr,
                                                   const int* __restrict__ srcs,
                                                   const float* __restrict__ bias,
                                                   unsigned short* __restrict__ Phi,
                                                   unsigned short* __restrict__ Plo) {
    int node = (blockIdx.x * blockDim.x + threadIdx.x) >> 6;
    if (node >= NN) return;
    int lane = threadIdx.x & 63;
    int head = lane >> 3;
    int b0 = indptr[node], e0 = indptr[node + 1];
    float edv = ed[node * NH + head];
    float4 a[4];
    float s[4];
    #pragma unroll
    for (int u = 0; u < 4; ++u) { a[u] = (float4){0.f, 0.f, 0.f, 0.f}; s[u] = 0.f; }
    int j = b0;
    for (; j + 3 < e0; j += 4) {
        #pragma unroll
        for (int u = 0; u < 4; ++u) {
            int x = srcs[j + u];
            float e = es[x * NH + head] + edv;
            e = (e > 0.f) ? e : 0.2f * e;
            float4 hv = *(const float4*)(H + (size_t)x * HID + lane * 4);
            float w = expf(e);
            s[u] += w;
            a[u].x = fmaf(w, hv.x, a[u].x); a[u].y = fmaf(w, hv.y, a[u].y);
            a[u].z = fmaf(w, hv.z, a[u].z); a[u].w = fmaf(w, hv.w, a[u].w);
        }
    }
    for (; j < e0; ++j) {
        int x = srcs[j];
        float e = es[x * NH + head] + edv;
        e = (e > 0.f) ? e : 0.2f * e;
        float4 hv = *(const float4*)(H + (size_t)x * HID + lane * 4);
        float w = expf(e);
        s[0] += w;
        a[0].x = fmaf(w, hv.x, a[0].x); a[0].y = fmaf(w, hv.y, a[0].y);
        a[0].z = fmaf(w, hv.z, a[0].z); a[0].w = fmaf(w, hv.w, a[0].w);
    }
    float sum = (s[0] + s[1]) + (s[2] + s[3]);
    float ax = (a[0].x + a[1].x) + (a[2].x + a[3].x);
    float ay = (a[0].y + a[1].y) + (a[2].y + a[3].y);
    float az = (a[0].z + a[1].z) + (a[2].z + a[3].z);
    float aw = (a[0].w + a[1].w) + (a[2].w + a[3].w);
    float inv = 1.f / (sum + 1e-16f);
    float4 bv = *(const float4*)(bias + lane * 4);
    float o[4];
    o[0] = fmaxf(fmaf(ax, inv, bv.x), 0.f);
    o[1] = fmaxf(fmaf(ay, inv, bv.y), 0.f);
    o[2] = fmaxf(fmaf(az, inv, bv.z), 0.f);
    o[3] = fmaxf(fmaf(aw, inv, bv.w), 0.f);
    ushort4 hv2, lv2;
    f2hilo(o[0], hv2.x, lv2.x); f2hilo(o[1], hv2.y, lv2.y);
    f2hilo(o[2], hv2.z, lv2.z); f2hilo(o[3], hv2.w, lv2.w);
    *(ushort4*)(Phi + (size_t)node * HID + lane * 4) = hv2;
    *(ushort4*)(Plo + (size_t)node * HID + lane * 4) = lv2;
}

// ---------------- per-graph max pool + linear head ----------------
__global__ void k_pool(const unsigned short* __restrict__ Phi,
                       const unsigned short* __restrict__ Plo,
                       const int* __restrict__ starts,
                       const float* __restrict__ fw, const float* __restrict__ fb,
                       float* __restrict__ out) {
    int g = (blockIdx.x * blockDim.x + threadIdx.x) >> 6;
    if (g >= GG) return;
    int lane = threadIdx.x & 63;
    int s = starts[g], e = starts[g + 1];
    float mx0 = -FLT_MAX, mx1 = -FLT_MAX, mx2 = -FLT_MAX, mx3 = -FLT_MAX;
    for (int n = s; n < e; ++n) {
        ushort4 hv = *(const ushort4*)(Phi + (size_t)n * HID + lane * 4);
        ushort4 lv = *(const ushort4*)(Plo + (size_t)n * HID + lane * 4);
        mx0 = fmaxf(mx0, bf2f(hv.x) + bf2f(lv.x));
        mx1 = fmaxf(mx1, bf2f(hv.y) + bf2f(lv.y));
        mx2 = fmaxf(mx2, bf2f(hv.z) + bf2f(lv.z));
        mx3 = fmaxf(mx3, bf2f(hv.w) + bf2f(lv.w));
    }
    float4 w = *(const float4*)(fw + lane * 4);
    float t = mx0 * w.x + mx1 * w.y + mx2 * w.z + mx3 * w.w;
    #pragma unroll
    for (int off = 32; off >= 1; off >>= 1) t += __shfl_xor(t, off, 64);
    if (lane == 0) out[g] = t + fb[0];
}

// ---------------- launcher ----------------
extern "C" void kernel_launch(void* const* d_in, const int* in_sizes, int n_in,
                              void* d_out, int out_size, void* d_ws, size_t ws_size,
                              hipStream_t stream) {
    const int* x_ids = (const int*)d_in[0];
    const int* eidx  = (const int*)d_in[1];
    const int* batch = (const int*)d_in[2];
    const float* emb = (const float*)d_in[3];
    const float* fw  = (const float*)d_in[4];
    const float* fb  = (const float*)d_in[5];
    const float* Wl[5], *asl[5], *adl[5], *bl[5];
    for (int l = 0; l < 5; ++l) {
        Wl[l]  = (const float*)d_in[6 + 4 * l];
        asl[l] = (const float*)d_in[7 + 4 * l];
        adl[l] = (const float*)d_in[8 + 4 * l];
        bl[l]  = (const float*)d_in[9 + 4 * l];
    }

    char* ws = (char*)d_ws;
    size_t off = 0;
    auto alloc = [&](size_t bytes) {
        void* p = ws + off;
        off = (off + bytes + 255) & ~(size_t)255;
        return p;
    };
    unsigned short* Phi  = (unsigned short*)alloc((size_t)NP * HID * 2);
    unsigned short* Plo  = (unsigned short*)alloc((size_t)NP * HID * 2);
    float* Q     = (float*)alloc((size_t)NN * HID * 4);
    unsigned short* Whi  = (unsigned short*)alloc((size_t)5 * HID * HID * 2);
    unsigned short* Wlo  = (unsigned short*)alloc((size_t)5 * HID * HID * 2);
    unsigned short* Wthi = (unsigned short*)alloc((size_t)5 * 16 * HID * 2);
    unsigned short* Wtlo = (unsigned short*)alloc((size_t)5 * 16 * HID * 2);
    float* es    = (float*)alloc((size_t)NN * NH * 4);
    float* ed    = (float*)alloc((size_t)NN * NH * 4);
    int* cnt     = (int*)alloc((size_t)NN * 4);
    int* cursor  = (int*)alloc((size_t)NN * 4);
    int* indptr  = (int*)alloc((size_t)(NN + 1) * 4);
    int* srcs    = (int*)alloc((size_t)EP * 4);
    int* bsum    = (int*)alloc((size_t)NB * 4);
    int* boff    = (int*)alloc((size_t)NB * 4);
    int* starts  = (int*)alloc((size_t)(GG + 1) * 4);
    (void)ws_size; (void)in_sizes; (void)n_in; (void)out_size;

    hipMemsetAsync(cnt, 0, (size_t)NN * 4, stream);
    hipMemsetAsync(cursor, 0, (size_t)NN * 4, stream);

    k_hist<<<(EP + 255) / 256, 256, 0, stream>>>(eidx + EE, cnt);
    k_scan1<<<NB, 256, 0, stream>>>(cnt, bsum);
    k_scan2<<<1, 128, 0, stream>>>(bsum, boff, indptr);
    k_scan3<<<NB, 256, 0, stream>>>(cnt, boff, indptr);
    k_fill<<<(EP + 255) / 256, 256, 0, stream>>>(eidx, eidx + EE, indptr, cursor, srcs);
    k_sortseg<<<(NN + 255) / 256, 256, 0, stream>>>(srcs, indptr);
    k_starts<<<(NN + 255) / 256, 256, 0, stream>>>(batch, starts);
    k_wconv<<<dim3(HID * HID / 256, 5), 256, 0, stream>>>(Wl[0], Wl[1], Wl[2], Wl[3], Wl[4], Whi, Wlo);
    k_wtilde<<<dim3(16, 5), 256, 0, stream>>>(Wl[0], Wl[1], Wl[2], Wl[3], Wl[4],
                                              asl[0], asl[1], asl[2], asl[3], asl[4],
                                              adl[0], adl[1], adl[2], adl[3], adl[4],
                                              Wthi, Wtlo);
    k_embed<<<NN / 4, 256, 0, stream>>>(x_ids, emb, Phi, Plo);

    for (int l = 0; l < 5; ++l) {
        dim3 gg(NP / 128, HID / 128);
        k_gemm<<<gg, 512, 0, stream>>>(Phi, Plo,
                                       Whi + (size_t)l * HID * HID,
                                       Wlo + (size_t)l * HID * HID,
                                       Wthi + (size_t)l * 16 * HID,
                                       Wtlo + (size_t)l * 16 * HID,
                                       Q, es, ed, NN);
        k_aggregate<<<NN / 2, 128, 0, stream>>>(Q, es, ed, indptr, srcs, bl[l], Phi, Plo);
    }
    k_pool<<<GG / 4, 256, 0, stream>>>(Phi, Plo, starts, fw, fb, (float*)d_out);
}

// Round 14
// 483.000 us; speedup vs baseline: 1.0155x; 1.0155x over previous
//
#include <hip/hip_runtime.h>
#include <float.h>
#include <math.h>

constexpr int NN  = 30000;   // nodes
constexpr int EE  = 300000;  // edges before self-loops
constexpr int GG  = 1024;    // graphs
constexpr int HID = 256;
constexpr int NH  = 8;       // heads
constexpr int EP  = EE + NN; // edges incl self-loops
constexpr int NGX = 240;     // padded M tiles (240*128 rows) for bijective XCD pairing
constexpr int NP  = NGX * 128;  // 30720 padded rows
constexpr int NB  = (NN + 255) / 256;  // 118 scan blocks

typedef short bf16x8 __attribute__((ext_vector_type(8)));
typedef float f32x4 __attribute__((ext_vector_type(4)));

__device__ __forceinline__ void gload_lds16(const void* g, void* l) {
    __builtin_amdgcn_global_load_lds(
        (const __attribute__((address_space(1))) unsigned int*)g,
        (__attribute__((address_space(3))) unsigned int*)l, 16, 0, 0);
}

__device__ __forceinline__ void f2hilo(float x, unsigned short& h, unsigned short& l) {
    unsigned u = __float_as_uint(x);
    h = (unsigned short)(u >> 16);                       // truncated hi
    float hv = __uint_as_float(u & 0xFFFF0000u);
    float r = x - hv;                                    // exact residual
    unsigned v = __float_as_uint(r);
    unsigned rnd = ((v >> 16) & 1u) + 0x7FFFu;           // RNE to bf16
    l = (unsigned short)((v + rnd) >> 16);
}

__device__ __forceinline__ float bf2f(unsigned short u) {
    return __uint_as_float(((unsigned)u) << 16);
}

// ---------------- CSR build ----------------
__global__ void k_hist(const int* __restrict__ edst, int* __restrict__ cnt) {
    int i = blockIdx.x * blockDim.x + threadIdx.x;
    if (i >= EP) return;
    int d = (i < EE) ? edst[i] : (i - EE);
    atomicAdd(&cnt[d], 1);
}

// parallel scan: per-block sums
__global__ void k_scan1(const int* __restrict__ cnt, int* __restrict__ bsum) {
    int tid = threadIdx.x, lane = tid & 63, wid = tid >> 6;
    int i = blockIdx.x * 256 + tid;
    int v = (i < NN) ? cnt[i] : 0;
    #pragma unroll
    for (int off = 32; off >= 1; off >>= 1) v += __shfl_xor(v, off, 64);
    __shared__ int ws[4];
    if (lane == 0) ws[wid] = v;
    __syncthreads();
    if (tid == 0) bsum[blockIdx.x] = ws[0] + ws[1] + ws[2] + ws[3];
}

// scan the 118 block sums (1 block, 128 threads)
__global__ void k_scan2(const int* __restrict__ bsum, int* __restrict__ boff,
                        int* __restrict__ indptr) {
    int tid = threadIdx.x, lane = tid & 63, wid = tid >> 6;
    int v = (tid < NB) ? bsum[tid] : 0;
    int incl = v;
    #pragma unroll
    for (int off = 1; off < 64; off <<= 1) {
        int t = __shfl_up(incl, off, 64);
        if (lane >= off) incl += t;
    }
    __shared__ int ws[2];
    if (lane == 63) ws[wid] = incl;
    __syncthreads();
    int pre = (wid == 1) ? ws[0] : 0;
    if (tid < NB) boff[tid] = pre + incl - v;  // exclusive
    if (tid == 0) indptr[NN] = ws[0] + ws[1];
}

// in-block exclusive scan + block offset
__global__ void k_scan3(const int* __restrict__ cnt, const int* __restrict__ boff,
                        int* __restrict__ indptr) {
    int tid = threadIdx.x, lane = tid & 63, wid = tid >> 6;
    int i = blockIdx.x * 256 + tid;
    int v = (i < NN) ? cnt[i] : 0;
    int incl = v;
    #pragma unroll
    for (int off = 1; off < 64; off <<= 1) {
        int t = __shfl_up(incl, off, 64);
        if (lane >= off) incl += t;
    }
    __shared__ int ws[4];
    if (lane == 63) ws[wid] = incl;
    __syncthreads();
    int pre = 0;
    for (int w = 0; w < wid; ++w) pre += ws[w];
    if (i < NN) indptr[i] = boff[blockIdx.x] + pre + incl - v;
}

__global__ void k_fill(const int* __restrict__ esrc, const int* __restrict__ edst,
                       const int* __restrict__ indptr, int* __restrict__ cursor,
                       int* __restrict__ srcs) {
    int i = blockIdx.x * blockDim.x + threadIdx.x;
    if (i >= EP) return;
    int d, s;
    if (i < EE) { d = edst[i]; s = esrc[i]; } else { d = i - EE; s = i - EE; }
    int pos = indptr[d] + atomicAdd(&cursor[d], 1);
    srcs[pos] = s;
}

// sort each segment -> deterministic slot order independent of atomic timing
__global__ void k_sortseg(int* __restrict__ srcs, const int* __restrict__ indptr) {
    int node = blockIdx.x * blockDim.x + threadIdx.x;
    if (node >= NN) return;
    int b = indptr[node], e = indptr[node + 1];
    for (int i = b + 1; i < e; ++i) {
        int v = srcs[i];
        int j = i - 1;
        while (j >= b && srcs[j] > v) { srcs[j + 1] = srcs[j]; --j; }
        srcs[j + 1] = v;
    }
}

__global__ void k_starts(const int* __restrict__ batch, int* __restrict__ starts) {
    int i = blockIdx.x * blockDim.x + threadIdx.x;
    if (i >= NN) return;
    int b = batch[i];
    if (i == 0 || batch[i - 1] != b) starts[b] = i;
    if (i == NN - 1) starts[GG] = NN;
}

// ---------------- weight split fp32 -> bf16 hi/lo ----------------
__global__ void k_wconv(const float* __restrict__ W1, const float* __restrict__ W2,
                        const float* __restrict__ W3, const float* __restrict__ W4,
                        const float* __restrict__ W5,
                        unsigned short* __restrict__ Whi, unsigned short* __restrict__ Wlo) {
    int i = blockIdx.x * blockDim.x + threadIdx.x;  // 0..65535
    int l = blockIdx.y;
    const float* W = (l == 0) ? W1 : (l == 1) ? W2 : (l == 2) ? W3 : (l == 3) ? W4 : W5;
    unsigned short h, lo;
    f2hilo(W[i], h, lo);
    Whi[(size_t)l * 65536 + i] = h;
    Wlo[(size_t)l * 65536 + i] = lo;
}

// folded score weights for all 5 layers in one launch:
// wt[l][t][k] = sum_c a[l][h,c]*W[l][h*32+c,k], t = h*2+type; bf16 hi/lo
__global__ void k_wtilde(const float* __restrict__ W1, const float* __restrict__ W2,
                         const float* __restrict__ W3, const float* __restrict__ W4,
                         const float* __restrict__ W5,
                         const float* __restrict__ as1, const float* __restrict__ as2,
                         const float* __restrict__ as3, const float* __restrict__ as4,
                         const float* __restrict__ as5,
                         const float* __restrict__ ad1, const float* __restrict__ ad2,
                         const float* __restrict__ ad3, const float* __restrict__ ad4,
                         const float* __restrict__ ad5,
                         unsigned short* __restrict__ Wthi, unsigned short* __restrict__ Wtlo) {
    int t = blockIdx.x;          // 0..15
    int l = blockIdx.y;          // 0..4
    int k = threadIdx.x;         // 0..255
    const float* W  = (l == 0) ? W1 : (l == 1) ? W2 : (l == 2) ? W3 : (l == 3) ? W4 : W5;
    const float* as = (l == 0) ? as1 : (l == 1) ? as2 : (l == 2) ? as3 : (l == 3) ? as4 : as5;
    const float* ad = (l == 0) ? ad1 : (l == 1) ? ad2 : (l == 2) ? ad3 : (l == 3) ? ad4 : ad5;
    int h = t >> 1, type = t & 1;
    const float* a = type ? ad : as;
    float v = 0.f;
    for (int c = 0; c < 32; ++c)
        v = fmaf(a[h * 32 + c], W[(size_t)(h * 32 + c) * HID + k], v);
    unsigned short hi, lo;
    f2hilo(v, hi, lo);
    Wthi[(size_t)l * 16 * HID + t * 256 + k] = hi;
    Wtlo[(size_t)l * 16 * HID + t * 256 + k] = lo;
}

// ---------------- embedding with max_norm=1 -> hi/lo ----------------
__global__ void k_embed(const int* __restrict__ ids, const float* __restrict__ emb,
                        unsigned short* __restrict__ Phi, unsigned short* __restrict__ Plo) {
    int w = (blockIdx.x * blockDim.x + threadIdx.x) >> 6;
    if (w >= NN) return;
    int lane = threadIdx.x & 63;
    const float4 v = *(const float4*)(emb + (size_t)ids[w] * HID + lane * 4);
    float ss = v.x * v.x + v.y * v.y + v.z * v.z + v.w * v.w;
    #pragma unroll
    for (int off = 32; off >= 1; off >>= 1) ss += __shfl_xor(ss, off, 64);
    float nrm = sqrtf(ss);
    float sc = fminf(1.0f, 1.0f / (nrm + 1e-12f));
    float o[4] = {v.x * sc, v.y * sc, v.z * sc, v.w * sc};
    ushort4 hv, lv;
    f2hilo(o[0], hv.x, lv.x); f2hilo(o[1], hv.y, lv.y);
    f2hilo(o[2], hv.z, lv.z); f2hilo(o[3], hv.w, lv.w);
    *(ushort4*)(Phi + (size_t)w * HID + lane * 4) = hv;
    *(ushort4*)(Plo + (size_t)w * HID + lane * 4) = lv;
}

// ---------------- split-bf16 MFMA GEMM + fused folded-score columns (R12 proven) ----------------
// 512 threads / 8 waves; single-buffer 64KB LDS (2 blocks/CU).
// 1-D grid with XCD-pairing decode: bid = 16*(x/8) + (x%8) + 8*y, so the two
// blocks sharing an A-tile (same x, y=0/1) differ by 8 -> same XCD under RR,
// dispatched adjacently -> second block's A staging hits that XCD's L2.
__global__ __launch_bounds__(512) void k_gemm(const unsigned short* __restrict__ Ahi,
                                              const unsigned short* __restrict__ Alo,
                                              const unsigned short* __restrict__ Bhi,
                                              const unsigned short* __restrict__ Blo,
                                              const unsigned short* __restrict__ Wthi,
                                              const unsigned short* __restrict__ Wtlo,
                                              float* __restrict__ O,
                                              float* __restrict__ es,
                                              float* __restrict__ ed, int M) {
    __shared__ unsigned short lds[4][128 * 64];  // Ahi, Alo, Bhi, Blo: 16KB each
    const int tid = threadIdx.x;
    const int bid = blockIdx.x;
    const int chunk = bid >> 4, within = bid & 15;
    const int bx = chunk * 8 + (within & 7);     // 0..239
    const int by = within >> 3;                  // 0..1
    const int m0 = bx * 128;
    const int n0 = by * 128;
    const int wid = tid >> 6, lane = tid & 63;
    const int wm = wid >> 1, wn = wid & 1;          // wm 0..3, wn 0..1
    const int r16 = lane & 15, kq = lane >> 4;
    const bool doScore = (by == 1);

    f32x4 acc[2][4];
    f32x4 acc_s[2];   // score accumulators: this wave handles ks == wn half of rows (wm, f)
    acc_s[0] = (f32x4){0.f, 0.f, 0.f, 0.f};
    acc_s[1] = (f32x4){0.f, 0.f, 0.f, 0.f};
    #pragma unroll
    for (int i = 0; i < 2; ++i)
        #pragma unroll
        for (int j = 0; j < 4; ++j) acc[i][j] = (f32x4){0.f, 0.f, 0.f, 0.f};

    for (int kt = 0; kt < 4; ++kt) {
        const int kk = kt * 64;
        #pragma unroll
        for (int rnd = 0; rnd < 2; ++rnd) {
            int q = rnd * 512 + tid;                 // 0..1023
            int row = q >> 3, c = q & 7;
            int sc = c ^ (row & 7);
            size_t goffA = (size_t)(m0 + row) * HID + kk + sc * 8;
            size_t goffB = (size_t)(n0 + row) * HID + kk + sc * 8;
            gload_lds16(Ahi + goffA, &lds[0][q * 8]);
            gload_lds16(Alo + goffA, &lds[1][q * 8]);
            gload_lds16(Bhi + goffB, &lds[2][q * 8]);
            gload_lds16(Blo + goffB, &lds[3][q * 8]);
        }
        __syncthreads();
        #pragma unroll
        for (int ks = 0; ks < 2; ++ks) {
            bf16x8 ah[2], al[2], bh[4], bl[4];
            #pragma unroll
            for (int f = 0; f < 2; ++f) {
                int rowa = wm * 32 + f * 16 + r16;
                int ca = (ks * 4 + kq) ^ (rowa & 7);
                int offa = rowa * 64 + ca * 8;
                ah[f] = *(const bf16x8*)&lds[0][offa];
                al[f] = *(const bf16x8*)&lds[1][offa];
            }
            #pragma unroll
            for (int f = 0; f < 4; ++f) {
                int rowb = wn * 64 + f * 16 + r16;
                int cb = (ks * 4 + kq) ^ (rowb & 7);
                int offb = rowb * 64 + cb * 8;
                bh[f] = *(const bf16x8*)&lds[2][offb];
                bl[f] = *(const bf16x8*)&lds[3][offb];
            }
            #pragma unroll
            for (int mi = 0; mi < 2; ++mi)
                #pragma unroll
                for (int ni = 0; ni < 4; ++ni) {
                    acc[mi][ni] = __builtin_amdgcn_mfma_f32_16x16x32_bf16(ah[mi], bh[ni], acc[mi][ni], 0, 0, 0);
                    acc[mi][ni] = __builtin_amdgcn_mfma_f32_16x16x32_bf16(ah[mi], bl[ni], acc[mi][ni], 0, 0, 0);
                    acc[mi][ni] = __builtin_amdgcn_mfma_f32_16x16x32_bf16(al[mi], bh[ni], acc[mi][ni], 0, 0, 0);
                }
            if (doScore && wn == ks) {
                const size_t wtoff = (size_t)r16 * HID + kk + ks * 32 + kq * 8;
                bf16x8 wth = *(const bf16x8*)(Wthi + wtoff);
                bf16x8 wtl = *(const bf16x8*)(Wtlo + wtoff);
                #pragma unroll
                for (int ml = 0; ml < 2; ++ml) {
                    acc_s[ml] = __builtin_amdgcn_mfma_f32_16x16x32_bf16(ah[ml], wth, acc_s[ml], 0, 0, 0);
                    acc_s[ml] = __builtin_amdgcn_mfma_f32_16x16x32_bf16(ah[ml], wtl, acc_s[ml], 0, 0, 0);
                    acc_s[ml] = __builtin_amdgcn_mfma_f32_16x16x32_bf16(al[ml], wth, acc_s[ml], 0, 0, 0);
                }
            }
        }
        __syncthreads();
    }
    // C/D layout: col = lane&15, row = (lane>>4)*4 + reg  [m89-verified]
    #pragma unroll
    for (int mi = 0; mi < 2; ++mi) {
        #pragma unroll
        for (int q = 0; q < 4; ++q) {
            int row = m0 + wm * 32 + mi * 16 + kq * 4 + q;
            if (row < M) {
                #pragma unroll
                for (int ni = 0; ni < 4; ++ni)
                    O[(size_t)row * HID + n0 + wn * 64 + ni * 16 + r16] = acc[mi][ni][q];
            }
        }
    }
    if (doScore) {
        // combine ks-halves per row-fragment (wm, ml): wn==1 writes partials, wn==0 adds + stores
        float* sl = (float*)&lds[0][0];  // 8KB scratch, main loop done
        if (wn == 1) {
            #pragma unroll
            for (int ml = 0; ml < 2; ++ml)
                *(f32x4*)&sl[((wm * 2 + ml) * 64 + lane) * 4] = acc_s[ml];
        }
        __syncthreads();
        if (wn == 0) {
            int h = r16 >> 1;
            #pragma unroll
            for (int ml = 0; ml < 2; ++ml) {
                f32x4 o = *(const f32x4*)&sl[((wm * 2 + ml) * 64 + lane) * 4];
                o += acc_s[ml];
                #pragma unroll
                for (int q = 0; q < 4; ++q) {
                    int row = m0 + wm * 32 + ml * 16 + kq * 4 + q;
                    if (row < M) {
                        if ((r16 & 1) == 0) es[row * NH + h] = o[q];
                        else               ed[row * NH + h] = o[q];
                    }
                }
            }
        }
    }
}

// ---------------- single-pass softmax-aggregate (R5 body; 2-wave blocks) ----------------
__global__ __launch_bounds__(128) void k_aggregate(const float* __restrict__ H,
                                                   const float* __restrict__ es,
                                                   const float* __restrict__ ed,
                                                   const int* __restrict__ indptr,
                                                   const int* __restrict__ srcs,
                                                   const float* __restrict__ bias,
                                                   unsigned short* __restrict__ Phi,
                                                   unsigned short* __restrict__ Plo) {
    int node = (blockIdx.x * blockDim.x + threadIdx.x) >> 6;
    if (node >= NN) return;
    int lane = threadIdx.x & 63;
    int head = lane >> 3;
    int b0 = indptr[node], e0 = indptr[node + 1];
    float edv = ed[node * NH + head];
    float4 a[4];
    float s[4];
    #pragma unroll
    for (int u = 0; u < 4; ++u) { a[u] = (float4){0.f, 0.f, 0.f, 0.f}; s[u] = 0.f; }
    int j = b0;
    for (; j + 3 < e0; j += 4) {
        #pragma unroll
        for (int u = 0; u < 4; ++u) {
            int x = srcs[j + u];
            float e = es[x * NH + head] + edv;
            e = (e > 0.f) ? e : 0.2f * e;
            float4 hv = *(const float4*)(H + (size_t)x * HID + lane * 4);
            float w = expf(e);
            s[u] += w;
            a[u].x = fmaf(w, hv.x, a[u].x); a[u].y = fmaf(w, hv.y, a[u].y);
            a[u].z = fmaf(w, hv.z, a[u].z); a[u].w = fmaf(w, hv.w, a[u].w);
        }
    }
    for (; j < e0; ++j) {
        int x = srcs[j];
        float e = es[x * NH + head] + edv;
        e = (e > 0.f) ? e : 0.2f * e;
        float4 hv = *(const float4*)(H + (size_t)x * HID + lane * 4);
        float w = expf(e);
        s[0] += w;
        a[0].x = fmaf(w, hv.x, a[0].x); a[0].y = fmaf(w, hv.y, a[0].y);
        a[0].z = fmaf(w, hv.z, a[0].z); a[0].w = fmaf(w, hv.w, a[0].w);
    }
    float sum = (s[0] + s[1]) + (s[2] + s[3]);
    float ax = (a[0].x + a[1].x) + (a[2].x + a[3].x);
    float ay = (a[0].y + a[1].y) + (a[2].y + a[3].y);
    float az = (a[0].z + a[1].z) + (a[2].z + a[3].z);
    float aw = (a[0].w + a[1].w) + (a[2].w + a[3].w);
    float inv = 1.f / (sum + 1e-16f);
    float4 bv = *(const float4*)(bias + lane * 4);
    float o[4];
    o[0] = fmaxf(fmaf(ax, inv, bv.x), 0.f);
    o[1] = fmaxf(fmaf(ay, inv, bv.y), 0.f);
    o[2] = fmaxf(fmaf(az, inv, bv.z), 0.f);
    o[3] = fmaxf(fmaf(aw, inv, bv.w), 0.f);
    ushort4 hv2, lv2;
    f2hilo(o[0], hv2.x, lv2.x); f2hilo(o[1], hv2.y, lv2.y);
    f2hilo(o[2], hv2.z, lv2.z); f2hilo(o[3], hv2.w, lv2.w);
    *(ushort4*)(Phi + (size_t)node * HID + lane * 4) = hv2;
    *(ushort4*)(Plo + (size_t)node * HID + lane * 4) = lv2;
}

// ---------------- per-graph max pool + linear head ----------------
__global__ void k_pool(const unsigned short* __restrict__ Phi,
                       const unsigned short* __restrict__ Plo,
                       const int* __restrict__ starts,
                       const float* __restrict__ fw, const float* __restrict__ fb,
                       float* __restrict__ out) {
    int g = (blockIdx.x * blockDim.x + threadIdx.x) >> 6;
    if (g >= GG) return;
    int lane = threadIdx.x & 63;
    int s = starts[g], e = starts[g + 1];
    float mx0 = -FLT_MAX, mx1 = -FLT_MAX, mx2 = -FLT_MAX, mx3 = -FLT_MAX;
    for (int n = s; n < e; ++n) {
        ushort4 hv = *(const ushort4*)(Phi + (size_t)n * HID + lane * 4);
        ushort4 lv = *(const ushort4*)(Plo + (size_t)n * HID + lane * 4);
        mx0 = fmaxf(mx0, bf2f(hv.x) + bf2f(lv.x));
        mx1 = fmaxf(mx1, bf2f(hv.y) + bf2f(lv.y));
        mx2 = fmaxf(mx2, bf2f(hv.z) + bf2f(lv.z));
        mx3 = fmaxf(mx3, bf2f(hv.w) + bf2f(lv.w));
    }
    float4 w = *(const float4*)(fw + lane * 4);
    float t = mx0 * w.x + mx1 * w.y + mx2 * w.z + mx3 * w.w;
    #pragma unroll
    for (int off = 32; off >= 1; off >>= 1) t += __shfl_xor(t, off, 64);
    if (lane == 0) out[g] = t + fb[0];
}

// ---------------- launcher ----------------
extern "C" void kernel_launch(void* const* d_in, const int* in_sizes, int n_in,
                              void* d_out, int out_size, void* d_ws, size_t ws_size,
                              hipStream_t stream) {
    const int* x_ids = (const int*)d_in[0];
    const int* eidx  = (const int*)d_in[1];
    const int* batch = (const int*)d_in[2];
    const float* emb = (const float*)d_in[3];
    const float* fw  = (const float*)d_in[4];
    const float* fb  = (const float*)d_in[5];
    const float* Wl[5], *asl[5], *adl[5], *bl[5];
    for (int l = 0; l < 5; ++l) {
        Wl[l]  = (const float*)d_in[6 + 4 * l];
        asl[l] = (const float*)d_in[7 + 4 * l];
        adl[l] = (const float*)d_in[8 + 4 * l];
        bl[l]  = (const float*)d_in[9 + 4 * l];
    }

    char* ws = (char*)d_ws;
    size_t off = 0;
    auto alloc = [&](size_t bytes) {
        void* p = ws + off;
        off = (off + bytes + 255) & ~(size_t)255;
        return p;
    };
    unsigned short* Phi  = (unsigned short*)alloc((size_t)NP * HID * 2);
    unsigned short* Plo  = (unsigned short*)alloc((size_t)NP * HID * 2);
    float* Q     = (float*)alloc((size_t)NN * HID * 4);
    unsigned short* Whi  = (unsigned short*)alloc((size_t)5 * HID * HID * 2);
    unsigned short* Wlo  = (unsigned short*)alloc((size_t)5 * HID * HID * 2);
    unsigned short* Wthi = (unsigned short*)alloc((size_t)5 * 16 * HID * 2);
    unsigned short* Wtlo = (unsigned short*)alloc((size_t)5 * 16 * HID * 2);
    float* es    = (float*)alloc((size_t)NN * NH * 4);
    float* ed    = (float*)alloc((size_t)NN * NH * 4);
    int* cnt     = (int*)alloc((size_t)NN * 4);
    int* cursor  = (int*)alloc((size_t)NN * 4);
    int* indptr  = (int*)alloc((size_t)(NN + 1) * 4);
    int* srcs    = (int*)alloc((size_t)EP * 4);
    int* bsum    = (int*)alloc((size_t)NB * 4);
    int* boff    = (int*)alloc((size_t)NB * 4);
    int* starts  = (int*)alloc((size_t)(GG + 1) * 4);
    (void)ws_size; (void)in_sizes; (void)n_in; (void)out_size;

    hipMemsetAsync(cnt, 0, (size_t)NN * 4, stream);
    hipMemsetAsync(cursor, 0, (size_t)NN * 4, stream);

    k_hist<<<(EP + 255) / 256, 256, 0, stream>>>(eidx + EE, cnt);
    k_scan1<<<NB, 256, 0, stream>>>(cnt, bsum);
    k_scan2<<<1, 128, 0, stream>>>(bsum, boff, indptr);
    k_scan3<<<NB, 256, 0, stream>>>(cnt, boff, indptr);
    k_fill<<<(EP + 255) / 256, 256, 0, stream>>>(eidx, eidx + EE, indptr, cursor, srcs);
    k_sortseg<<<(NN + 255) / 256, 256, 0, stream>>>(srcs, indptr);
    k_starts<<<(NN + 255) / 256, 256, 0, stream>>>(batch, starts);
    k_wconv<<<dim3(HID * HID / 256, 5), 256, 0, stream>>>(Wl[0], Wl[1], Wl[2], Wl[3], Wl[4], Whi, Wlo);
    k_wtilde<<<dim3(16, 5), 256, 0, stream>>>(Wl[0], Wl[1], Wl[2], Wl[3], Wl[4],
                                              asl[0], asl[1], asl[2], asl[3], asl[4],
                                              adl[0], adl[1], adl[2], adl[3], adl[4],
                                              Wthi, Wtlo);
    k_embed<<<NN / 4, 256, 0, stream>>>(x_ids, emb, Phi, Plo);

    for (int l = 0; l < 5; ++l) {
        k_gemm<<<NGX * 2, 512, 0, stream>>>(Phi, Plo,
                                            Whi + (size_t)l * HID * HID,
                                            Wlo + (size_t)l * HID * HID,
                                            Wthi + (size_t)l * 16 * HID,
                                            Wtlo + (size_t)l * 16 * HID,
                                            Q, es, ed, NN);
        k_aggregate<<<NN / 2, 128, 0, stream>>>(Q, es, ed, indptr, srcs, bl[l], Phi, Plo);
    }
    k_pool<<<GG / 4, 256, 0, stream>>>(Phi, Plo, starts, fw, fb, (float*)d_out);
}